// Round 11
// baseline (205.527 us; speedup 1.0000x reference)
//
#include <hip/hip_runtime.h>
#include <math.h>

#define BATCH    65536
#define FEAT     512
#define NCLASS   16
#define LAMDA    1.0f
#define LAMDA1   10.0f
#define SCALE    1.0f
#define EPS      1e-9f

constexpr int BLOCK  = 256;
constexpr int OGRID  = 4096;               // logical grid (partials layout, bit-exact)
constexpr int PAIR   = 4;                  // logical blocks per physical block
constexpr int GRID2  = OGRID / PAIR;       // 1024 physical streaming blocks
constexpr int NV     = BATCH * (FEAT / 4); // 8,388,608 float4 elements
constexpr int STRIDE = OGRID * BLOCK;      // 1,048,576 — UNCHANGED element mapping
constexpr int ITERS  = NV / STRIDE;        // 8 per logical block — UNCHANGED

// Workspace layout (float slots):
//   [0, OGRID)  : per-logical-block partial sums (same 4096 slots as always)
//   [OGRID]     : item1 (gram cosine sum)
constexpr int WS_ITEM1 = OGRID;

typedef float f4v __attribute__((ext_vector_type(4)));

// ---------------------------------------------------------------------------
// R10 lesson: 1024-thread blocks HURT (204.9 vs R8's 199.5) — the waves/CU
// ceiling wasn't binding; 16-wave barrier gangs + exact-fit placement cost
// more than the extra waves buy. Revert to 256-thread blocks.
// The only axis with a measured win is CHURN (R8: PAIR=2, -4 us). Model:
// ~2 us one-shot blocks are dispatch-limited (~1.8 resident/CU, no resource
// cap); residency scales with block lifetime. R11: PAIR=4 — each physical
// block runs 4 logical R0-blocks sequentially, straight-line, before its
// epilogue. Same validated structure as R8 (compiler-scheduled nt loads,
// no asm, no deep pipelines). Per-logical-block per-thread arithmetic,
// shuffle tree, wsum order, partials layout: IDENTICAL -> bit-exact.
// ---------------------------------------------------------------------------
__global__ __launch_bounds__(BLOCK) void island_main(
    const f4v* __restrict__ x,         // [BATCH * FEAT/4]
    const int* __restrict__ y,         // [BATCH]
    const f4v* __restrict__ centers4,  // [NCLASS * FEAT/4]
    float*     __restrict__ ws)        // see layout above
{
    __shared__ float wsum[4];
    __shared__ float gram[NCLASS][NCLASS];

    const int bid  = blockIdx.x;
    const int t    = threadIdx.x;
    const int lane = t & 63;
    const int wid  = t >> 6;

    if (bid < GRID2) {
        // ---------------- four logical blocks, straight-line --------------
        const int d4 = t & 127;
        float sums[PAIR];

        #pragma unroll
        for (int p = 0; p < PAIR; ++p) {
            const int lb  = bid + p * GRID2;       // logical block id
            const int tid = lb * BLOCK + t;

            // wave-uniform sample-row base -> y loads become s_loads.
            const int base_b = __builtin_amdgcn_readfirstlane(tid >> 7);

            int cls[ITERS];
            #pragma unroll
            for (int it = 0; it < ITERS; ++it)
                cls[it] = y[base_b + it * (STRIDE >> 7)];

            float sum = 0.0f;
            #pragma unroll
            for (int it = 0; it < ITERS; ++it) {
                // nt on the x stream (R4: plain loads thrash L1/L2 and evict
                // the centers table). Compiler schedules the 8 loads.
                f4v xv = __builtin_nontemporal_load(&x[tid + it * STRIDE]);
                f4v cv = centers4[cls[it] * (FEAT / 4) + d4];
                f4v e  = xv - cv;
                sum += e.x * e.x + e.y * e.y + e.z * e.z + e.w * e.w;
            }
            sums[p] = sum;
        }

        // ---------------- reductions (exact original tree/order) ----------
        #pragma unroll
        for (int p = 0; p < PAIR; ++p) {
            float sum = sums[p];
            #pragma unroll
            for (int off = 32; off > 0; off >>= 1)
                sum += __shfl_down(sum, off, 64);
            if (lane == 0) wsum[wid] = sum;
            __syncthreads();
            if (t == 0)
                ws[bid + p * GRID2] = wsum[0] + wsum[1] + wsum[2] + wsum[3];
            __syncthreads();   // wsum reuse (write-after-read)
        }
    } else {
        // ---------------- gram + item1 (hidden under the stream) ----------
        const int j = t >> 4;
        const int k = t & 15;
        const f4v* cj = centers4 + j * (FEAT / 4);
        const f4v* ck = centers4 + k * (FEAT / 4);
        float dot = 0.0f;
        #pragma unroll 8
        for (int i = 0; i < FEAT / 4; ++i) {
            f4v a = cj[i];
            f4v b = ck[i];
            dot += a.x * b.x + a.y * b.y + a.z * b.z + a.w * b.w;
        }
        gram[j][k] = dot;
        __syncthreads();

        if (t == 0) {
            // EXACT old-finalize item1 arithmetic/order.
            float item1 = 0.0f;
            for (int jj = 0; jj < NCLASS; ++jj) {
                float nj = sqrtf(gram[jj][jj]);
                for (int kk = jj + 1; kk < NCLASS; ++kk) {
                    float nk = sqrtf(gram[kk][kk]);
                    item1 += gram[jj][kk] / (nj * nk + EPS) + 1.0f;
                }
            }
            ws[WS_ITEM1] = item1;
        }
    }
}

// ---------------------------------------------------------------------------
// Kernel 2 (single block): bare 4096-partial reduce + combine. ~2-3 us.
// Same reduction order as all previous rounds -> bit-identical result.
// ---------------------------------------------------------------------------
__global__ __launch_bounds__(256) void finalize_kernel(
    const float* __restrict__ ws,   // partials [OGRID] + item1 at [WS_ITEM1]
    float*       __restrict__ out)  // [1]
{
    float psum = 0.0f;
    #pragma unroll
    for (int k = 0; k < OGRID / 256; ++k)
        psum += ws[threadIdx.x + k * 256];
    #pragma unroll
    for (int off = 32; off > 0; off >>= 1)
        psum += __shfl_down(psum, off, 64);

    __shared__ float wsum[4];
    const int lane = threadIdx.x & 63;
    const int wid  = threadIdx.x >> 6;
    if (lane == 0) wsum[wid] = psum;
    __syncthreads();

    if (threadIdx.x == 0) {
        float total = wsum[0] + wsum[1] + wsum[2] + wsum[3];
        float loss_center = 0.5f * total * (SCALE / (float)BATCH);
        out[0] = LAMDA * (loss_center + LAMDA1 * ws[WS_ITEM1]);
    }
}

extern "C" void kernel_launch(void* const* d_in, const int* in_sizes, int n_in,
                              void* d_out, int out_size, void* d_ws, size_t ws_size,
                              hipStream_t stream) {
    const float* x       = (const float*)d_in[0];   // [BATCH, FEAT]
    const int*   y       = (const int*)d_in[1];     // [BATCH]
    const float* centers = (const float*)d_in[2];   // [NCLASS, FEAT]
    float* out = (float*)d_out;
    float* ws  = (float*)d_ws;

    island_main<<<GRID2 + 1, BLOCK, 0, stream>>>(
        (const f4v*)x, y, (const f4v*)centers, ws);

    finalize_kernel<<<1, 256, 0, stream>>>(ws, out);
}

// Round 12
// 202.521 us; speedup vs baseline: 1.0148x; 1.0148x over previous
//
#include <hip/hip_runtime.h>
#include <math.h>

#define BATCH    65536
#define FEAT     512
#define NCLASS   16
#define LAMDA    1.0f
#define LAMDA1   10.0f
#define SCALE    1.0f
#define EPS      1e-9f

constexpr int BLOCK  = 256;
constexpr int OGRID  = 4096;               // logical grid (partials layout, bit-exact)
constexpr int PAIR   = 2;                  // logical blocks per physical block (OPTIMAL)
constexpr int GRID2  = OGRID / PAIR;       // 2048 physical streaming blocks
constexpr int NV     = BATCH * (FEAT / 4); // 8,388,608 float4 elements
constexpr int STRIDE = OGRID * BLOCK;      // 1,048,576 — UNCHANGED element mapping
constexpr int ITERS  = NV / STRIDE;        // 8 per logical block — UNCHANGED

// Workspace layout (float slots):
//   [0, OGRID)  : per-logical-block partial sums (same 4096 slots as always)
//   [OGRID]     : item1 (gram cosine sum)
constexpr int WS_ITEM1 = OGRID;

typedef float f4v __attribute__((ext_vector_type(4)));

// ---------------------------------------------------------------------------
// FINAL CONFIGURATION (measured optimum across R0-R11):
//   churn curve: PAIR=1 -> 203.0 us, PAIR=2 -> 199.5 us, PAIR=4 -> 205.5 us.
//   PAIR=2 amortizes block churn; PAIR=4 loses to tail exposure (4/CU exact
//   fit, no dispatch slack). 1024-thread blocks (R10): worse (204.9) — the
//   waves/CU ceiling was not binding. Forced 16-deep MLP (R5): neutral.
//   LDS return path (R7): -10%. Plain caching loads (R4): thrash L1/L2,
//   evict centers table; FETCH_SIZE invariant at 67.7 MB either way. Fences
//   (R1) and single-kernel atomic termination (R2): large regressions.
// Remaining time: 2 x ~78 us harness ws-poison fills (86% HBM peak, outside
// kernel control) + ~42 us stream (~3.2 TB/s effective, survived MLP/return-
// path/cache/occupancy/churn interventions) + ~2 us finalize.
// ---------------------------------------------------------------------------
__global__ __launch_bounds__(BLOCK) void island_main(
    const f4v* __restrict__ x,         // [BATCH * FEAT/4]
    const int* __restrict__ y,         // [BATCH]
    const f4v* __restrict__ centers4,  // [NCLASS * FEAT/4]
    float*     __restrict__ ws)        // see layout above
{
    __shared__ float wsum[4];
    __shared__ float gram[NCLASS][NCLASS];

    const int bid  = blockIdx.x;
    const int t    = threadIdx.x;
    const int lane = t & 63;
    const int wid  = t >> 6;

    if (bid < GRID2) {
        // ---------------- two logical blocks, straight-line ---------------
        const int d4 = t & 127;
        float sums[PAIR];

        #pragma unroll
        for (int p = 0; p < PAIR; ++p) {
            const int lb  = bid + p * GRID2;       // logical block id
            const int tid = lb * BLOCK + t;

            // wave-uniform sample-row base -> y loads become s_loads.
            const int base_b = __builtin_amdgcn_readfirstlane(tid >> 7);

            int cls[ITERS];
            #pragma unroll
            for (int it = 0; it < ITERS; ++it)
                cls[it] = y[base_b + it * (STRIDE >> 7)];

            float sum = 0.0f;
            #pragma unroll
            for (int it = 0; it < ITERS; ++it) {
                // nt on the x stream (R4: plain loads thrash L1/L2 and evict
                // the centers table). Compiler schedules the 8 loads.
                f4v xv = __builtin_nontemporal_load(&x[tid + it * STRIDE]);
                f4v cv = centers4[cls[it] * (FEAT / 4) + d4];
                f4v e  = xv - cv;
                sum += e.x * e.x + e.y * e.y + e.z * e.z + e.w * e.w;
            }
            sums[p] = sum;
        }

        // ---------------- reductions (exact original tree/order) ----------
        #pragma unroll
        for (int p = 0; p < PAIR; ++p) {
            float sum = sums[p];
            #pragma unroll
            for (int off = 32; off > 0; off >>= 1)
                sum += __shfl_down(sum, off, 64);
            if (lane == 0) wsum[wid] = sum;
            __syncthreads();
            if (t == 0)
                ws[bid + p * GRID2] = wsum[0] + wsum[1] + wsum[2] + wsum[3];
            __syncthreads();   // wsum reuse (write-after-read)
        }
    } else {
        // ---------------- gram + item1 (hidden under the stream) ----------
        const int j = t >> 4;
        const int k = t & 15;
        const f4v* cj = centers4 + j * (FEAT / 4);
        const f4v* ck = centers4 + k * (FEAT / 4);
        float dot = 0.0f;
        #pragma unroll 8
        for (int i = 0; i < FEAT / 4; ++i) {
            f4v a = cj[i];
            f4v b = ck[i];
            dot += a.x * b.x + a.y * b.y + a.z * b.z + a.w * b.w;
        }
        gram[j][k] = dot;
        __syncthreads();

        if (t == 0) {
            // EXACT old-finalize item1 arithmetic/order.
            float item1 = 0.0f;
            for (int jj = 0; jj < NCLASS; ++jj) {
                float nj = sqrtf(gram[jj][jj]);
                for (int kk = jj + 1; kk < NCLASS; ++kk) {
                    float nk = sqrtf(gram[kk][kk]);
                    item1 += gram[jj][kk] / (nj * nk + EPS) + 1.0f;
                }
            }
            ws[WS_ITEM1] = item1;
        }
    }
}

// ---------------------------------------------------------------------------
// Kernel 2 (single block): bare 4096-partial reduce + combine. ~2-3 us.
// Same reduction order as all previous rounds -> bit-identical result.
// ---------------------------------------------------------------------------
__global__ __launch_bounds__(256) void finalize_kernel(
    const float* __restrict__ ws,   // partials [OGRID] + item1 at [WS_ITEM1]
    float*       __restrict__ out)  // [1]
{
    float psum = 0.0f;
    #pragma unroll
    for (int k = 0; k < OGRID / 256; ++k)
        psum += ws[threadIdx.x + k * 256];
    #pragma unroll
    for (int off = 32; off > 0; off >>= 1)
        psum += __shfl_down(psum, off, 64);

    __shared__ float wsum[4];
    const int lane = threadIdx.x & 63;
    const int wid  = threadIdx.x >> 6;
    if (lane == 0) wsum[wid] = psum;
    __syncthreads();

    if (threadIdx.x == 0) {
        float total = wsum[0] + wsum[1] + wsum[2] + wsum[3];
        float loss_center = 0.5f * total * (SCALE / (float)BATCH);
        out[0] = LAMDA * (loss_center + LAMDA1 * ws[WS_ITEM1]);
    }
}

extern "C" void kernel_launch(void* const* d_in, const int* in_sizes, int n_in,
                              void* d_out, int out_size, void* d_ws, size_t ws_size,
                              hipStream_t stream) {
    const float* x       = (const float*)d_in[0];   // [BATCH, FEAT]
    const int*   y       = (const int*)d_in[1];     // [BATCH]
    const float* centers = (const float*)d_in[2];   // [NCLASS, FEAT]
    float* out = (float*)d_out;
    float* ws  = (float*)d_ws;

    island_main<<<GRID2 + 1, BLOCK, 0, stream>>>(
        (const f4v*)x, y, (const f4v*)centers, ws);

    finalize_kernel<<<1, 256, 0, stream>>>(ws, out);
}